// Round 4
// baseline (633.560 us; speedup 1.0000x reference)
//
#include <hip/hip_runtime.h>

#define PI_F 3.14159265358979323846f

__device__ __forceinline__ float2 cmulf(float2 a, float c, float s) {
    return make_float2(a.x * c - a.y * s, a.x * s + a.y * c);
}

// Radix-4 butterfly, +i (inverse), Stockham/DIT style (twiddle-free form).
#define BFLY4(v0, v1, v2, v3, o0, o1, o2, o3)                                  \
    {                                                                          \
        float a0r = v0.x + v2.x, a0i = v0.y + v2.y;                            \
        float a1r = v0.x - v2.x, a1i = v0.y - v2.y;                            \
        float a2r = v1.x + v3.x, a2i = v1.y + v3.y;                            \
        float a3r = v1.x - v3.x, a3i = v1.y - v3.y;                            \
        o0 = make_float2(a0r + a2r, a0i + a2i);                                \
        o1 = make_float2(a1r - a3i, a1i + a3r);                                \
        o2 = make_float2(a0r - a2r, a0i - a2i);                                \
        o3 = make_float2(a1r + a3i, a1i - a3r);                                \
    }

// In-place DIF radix-4 butterfly (+i), POST-twiddles w^j, w^{2j}, w^{3j}.
// F0=t0+t2; F1=t1+i*t3; F2=t0-t2; F3=t1-i*t3; out_r = F_r * w1^r.
#define DIF4(z0, z1, z2, z3, w1c, w1s)                                         \
    {                                                                          \
        float t0r = z0.x + z2.x, t0i = z0.y + z2.y;                            \
        float t1r = z0.x - z2.x, t1i = z0.y - z2.y;                            \
        float t2r = z1.x + z3.x, t2i = z1.y + z3.y;                            \
        float t3r = z1.x - z3.x, t3i = z1.y - z3.y;                            \
        float w2c = (w1c) * (w1c) - (w1s) * (w1s), w2s = 2.0f * (w1c) * (w1s); \
        float w3c = (w1c) * w2c - (w1s) * w2s,  w3s = (w1c) * w2s + (w1s) * w2c;\
        z0 = make_float2(t0r + t2r, t0i + t2i);                                \
        float u1r = t1r - t3i, u1i = t1i + t3r;                                \
        z1 = make_float2(u1r * (w1c) - u1i * (w1s), u1r * (w1s) + u1i * (w1c));\
        float u2r = t0r - t2r, u2i = t0i - t2i;                                \
        z2 = make_float2(u2r * w2c - u2i * w2s, u2r * w2s + u2i * w2c);        \
        float u3r = t1r + t3i, u3i = t1i - t3r;                                \
        z3 = make_float2(u3r * w3c - u3i * w3s, u3r * w3s + u3i * w3c);        \
    }

// Twiddle-free in-place DIF radix-4 (j = 0 columns).
#define DIF4_NT(z0, z1, z2, z3)                                                \
    {                                                                          \
        float t0r = z0.x + z2.x, t0i = z0.y + z2.y;                            \
        float t1r = z0.x - z2.x, t1i = z0.y - z2.y;                            \
        float t2r = z1.x + z3.x, t2i = z1.y + z3.y;                            \
        float t3r = z1.x - z3.x, t3i = z1.y - z3.y;                            \
        z0 = make_float2(t0r + t2r, t0i + t2i);                                \
        z1 = make_float2(t1r - t3i, t1i + t3r);                                \
        z2 = make_float2(t0r - t2r, t0i - t2i);                                \
        z3 = make_float2(t1r + t3i, t1i - t3r);                                \
    }

// LDS float2-index swizzle (verified round 2; conflict-free).
#define SW(e) ((e) ^ ((((e) >> 4) & 3) * 5))

// ---------------------------------------------------------------------------
// K1: one workgroup (512 threads) = one row of length 4096.  (VERIFIED)
// Makhoul half-spectrum + 2048-pt complex IFFT (Stockham radix-4).
// ---------------------------------------------------------------------------
template<bool IDXST>
__global__ __launch_bounds__(512, 8)
void row_fft_kernel(const float* __restrict__ in, float* __restrict__ out,
                    const float2* __restrict__ expk)
{
    __shared__ float smem[8192];               // 32 KB
    float*  xs   = smem;
    float2* bufB = (float2*)smem;
    float2* bufA = (float2*)(smem + 4096);

    const int t = threadIdx.x;                 // 0..511
    const size_t row = blockIdx.x;
    const float* src = in  + row * 4096;
    float*       dst = out + row * 4096;

    {
        const float4* s4 = (const float4*)src;
        float4* x4 = (float4*)xs;
        x4[t]       = s4[t];
        x4[t + 512] = s4[t + 512];
    }
    __syncthreads();

    float2 z[4];
    #pragma unroll
    for (int i = 0; i < 4; i++) {
        int k = t + 512 * i;                   // 0..2047
        float Xa, Xra, Xb, Xrb;
        if (IDXST) {
            Xa  = xs[(4096 - k) & 4095];
            Xra = xs[k];
            Xb  = xs[2048 - k];
            Xrb = xs[2048 + k];
            if (k == 0) { Xa = 0.0f; Xra = 0.0f; }
        } else {
            Xa  = xs[k];
            Xra = xs[(4096 - k) & 4095];
            Xb  = xs[2048 + k];
            Xrb = xs[2048 - k];
            if (k == 0) Xra = 0.0f;
        }
        float2 ea = expk[k];
        float2 eb = expk[k + 2048];
        float Var = 0.5f * (Xa * ea.x + Xra * ea.y);
        float Vai = 0.5f * (Xa * ea.y - Xra * ea.x);
        float Vbr = 0.5f * (Xb * eb.x + Xrb * eb.y);
        float Vbi = 0.5f * (Xb * eb.y - Xrb * eb.x);
        float Ar = Var + Vbr, Ai = Vai + Vbi;
        float Dr = Var - Vbr, Di = Vai - Vbi;
        float cw, sw;
        __sincosf(PI_F * (float)k * (1.0f / 2048.0f), &sw, &cw);
        float Br = Dr * cw - Di * sw;
        float Bi = Dr * sw + Di * cw;
        z[i] = make_float2(Ar - Bi, Ai + Br);
    }

    {
        float2 v0 = z[0], v1 = z[1], v2 = z[2], v3 = z[3];
        int e = t << 2;
        BFLY4(v0, v1, v2, v3,
              bufA[SW(e)], bufA[SW(e + 1)], bufA[SW(e + 2)], bufA[SW(e + 3)]);
    }
    __syncthreads();

    float2* sb = bufA;
    float2* db = bufB;
    int Ns = 4;
    #pragma unroll
    for (int s = 1; s < 5; s++) {
        const int ls = 2 * s;
        const int j = t;
        float2 v0 = sb[SW(j)];
        float2 v1 = sb[SW(j + 512)];
        float2 v2 = sb[SW(j + 1024)];
        float2 v3 = sb[SW(j + 1536)];
        int jm = j & (Ns - 1);
        float c1, s1;
        if (s <= 2) {
            float2 e1 = expk[jm << (12 - 2 * s)];
            c1 = e1.x; s1 = e1.y;
        } else {
            __sincosf((0.5f * PI_F) * (float)jm / (float)Ns, &s1, &c1);
        }
        float c2 = c1 * c1 - s1 * s1, s2 = 2.0f * c1 * s1;
        float c3 = c1 * c2 - s1 * s2, s3 = c1 * s2 + s1 * c2;
        v1 = cmulf(v1, c1, s1);
        v2 = cmulf(v2, c2, s2);
        v3 = cmulf(v3, c3, s3);
        int idxD = ((j >> ls) << (ls + 2)) | jm;
        BFLY4(v0, v1, v2, v3,
              db[SW(idxD)], db[SW(idxD + Ns)],
              db[SW(idxD + 2 * Ns)], db[SW(idxD + 3 * Ns)]);
        __syncthreads();
        float2* tmp = sb; sb = db; db = tmp;
        Ns <<= 2;
    }

    {
        int j  = t;
        int jB = 1023 - t;
        float2 a0 = sb[SW(j)];
        float2 a1 = sb[SW(j + 1024)];
        float2 b0 = sb[SW(jB)];
        float2 b1 = sb[SW(jB + 1024)];
        float sA, cA, sB, cB;
        __sincosf(PI_F * (float)j  * (1.0f / 1024.0f), &sA, &cA);
        __sincosf(PI_F * (float)jB * (1.0f / 1024.0f), &sB, &cB);
        float2 wa1 = cmulf(a1, cA, sA);
        float2 wb1 = cmulf(b1, cB, sB);
        float2 zA0 = make_float2(a0.x + wa1.x, a0.y + wa1.y);
        float2 zA1 = make_float2(a0.x - wa1.x, a0.y - wa1.y);
        float2 zB0 = make_float2(b0.x + wb1.x, b0.y + wb1.y);
        float2 zB1 = make_float2(b0.x - wb1.x, b0.y - wb1.y);
        float4 oA, oB;
        if (IDXST) {
            oA = make_float4(zA0.x, -zB1.y, zA0.y, -zB1.x);
            oB = make_float4(zB0.x, -zA1.y, zB0.y, -zA1.x);
        } else {
            oA = make_float4(zA0.x,  zB1.y, zA0.y,  zB1.x);
            oB = make_float4(zB0.x,  zA1.y, zB0.y,  zA1.x);
        }
        float4* d4 = (float4*)dst;
        d4[j]  = oA;
        d4[jB] = oB;
    }
}

// ---------------------------------------------------------------------------
// Four-step column IDCT along M (length 4096), transpose-free.
// 2048-pt IFFT over k = 64*m1 + m2 (m1<32, m2<64), output n = n1 + 32*n2:
//   P1: DFT-32 over m1 (in registers) + four-step twiddle  -> W[64*n1 + m2]
//   P2: DFT-64 over m2 (in registers) + fused de-interleave -> Y
// All global accesses lane-contiguous (>=256 B per wave).
// ---------------------------------------------------------------------------

__global__ __launch_bounds__(256, 3)
void col_pass1(const float* __restrict__ g, float2* __restrict__ wbuf,
               const float2* __restrict__ expk)
{
    const int col = blockIdx.x * 64 + threadIdx.x;       // lanes = cols
    const int m2  = blockIdx.y * 4 + threadIdx.y;        // wave-uniform, 0..63
    const float* G = g    + (size_t)blockIdx.z * 4096 * 4096;
    float2*      W = wbuf + (size_t)blockIdx.z * 2048 * 4096;

    const float2 u = expk[4 * m2];                       // e^{i pi m2/2048}

    float2 z[32];

    // ---- Z-build (Makhoul IDCT prologue along M), k = 64*m1 + m2 ----
    #pragma unroll
    for (int m1 = 0; m1 < 32; m1++) {
        int k = 64 * m1 + m2;                            // 0..2047
        float Xa  = G[(size_t)k * 4096 + col];
        float Xra = (k == 0) ? 0.0f : G[(size_t)(4096 - k) * 4096 + col];
        float Xb  = G[(size_t)(2048 + k) * 4096 + col];
        float Xrb = G[(size_t)(2048 - k) * 4096 + col];
        float2 ea = expk[k];
        float2 eb = expk[k + 2048];
        float Var = 0.5f * (Xa * ea.x + Xra * ea.y);
        float Vai = 0.5f * (Xa * ea.y - Xra * ea.x);
        float Vbr = 0.5f * (Xb * eb.x + Xrb * eb.y);
        float Vbi = 0.5f * (Xb * eb.y - Xrb * eb.x);
        float Ar = Var + Vbr, Ai = Vai + Vbi;
        float Dr = Var - Vbr, Di = Vai - Vbi;
        // e^{i pi k/2048} = u * e^{i pi m1/32};  e^{i pi m1/32} from table:
        // m1<16: expk[256*m1]; m1>=16: i*expk[256*(m1-16)]
        float2 ev = expk[256 * (m1 & 15)];
        float vc = (m1 < 16) ? ev.x : -ev.y;
        float vs = (m1 < 16) ? ev.y :  ev.x;
        float cw = u.x * vc - u.y * vs;
        float sw = u.x * vs + u.y * vc;
        float Br = Dr * cw - Di * sw;
        float Bi = Dr * sw + Di * cw;
        z[m1] = make_float2(Ar - Bi, Ai + Br);
    }

    // ---- in-place DIF DFT-32 (+i), radices [4,4,2] ----
    // stage 1: len=32, q=8; w1 = e^{2 pi i j/32} = expk[512 j]
    #pragma unroll
    for (int j = 0; j < 8; j++) {
        if (j == 0) { DIF4_NT(z[0], z[8], z[16], z[24]); }
        else {
            float2 e1 = expk[512 * j];
            DIF4(z[j], z[j + 8], z[j + 16], z[j + 24], e1.x, e1.y);
        }
    }
    // stage 2: len=8, q=2; j=0 twiddle-free, j=1 w1 = e^{i pi/4}
    #pragma unroll
    for (int b = 0; b < 32; b += 8) {
        DIF4_NT(z[b], z[b + 2], z[b + 4], z[b + 6]);
        DIF4(z[b + 1], z[b + 3], z[b + 5], z[b + 7],
             0.70710678118654752f, 0.70710678118654752f);
    }
    // stage 3: radix-2 on adjacent pairs
    #pragma unroll
    for (int m = 0; m < 32; m += 2) {
        float2 a = z[m], b = z[m + 1];
        z[m]     = make_float2(a.x + b.x, a.y + b.y);
        z[m + 1] = make_float2(a.x - b.x, a.y - b.y);
    }
    // position p holds Zhat[k], k = (p>>3) + 4*((p>>1)&3) + 16*(p&1)

    // ---- four-step twiddle e^{2 pi i n1 m2/2048} (incremental) + store ----
    const float2 r0 = expk[8 * m2];                      // e^{2 pi i m2/2048}
    float ct = 1.0f, st = 0.0f;
    #pragma unroll
    for (int n1 = 0; n1 < 32; n1++) {
        // inverse digit-reversal: position holding Zhat[n1]
        int p = 8 * (n1 & 3) + 2 * ((n1 >> 2) & 3) + (n1 >> 4);
        W[(size_t)(64 * n1 + m2) * 4096 + col] = cmulf(z[p], ct, st);
        float nc = ct * r0.x - st * r0.y;
        float ns = ct * r0.y + st * r0.x;
        ct = nc; st = ns;
    }
}

__global__ __launch_bounds__(256, 3)
void col_pass2(const float2* __restrict__ wbuf, float* __restrict__ y,
               const float2* __restrict__ expk)
{
    const int col = blockIdx.x * 64 + threadIdx.x;
    const int n1  = blockIdx.y * 4 + threadIdx.y;        // 0..31
    const float2* W = wbuf + (size_t)blockIdx.z * 2048 * 4096;
    float*        Y = y    + (size_t)blockIdx.z * 4096 * 4096;

    float2 z[64];
    #pragma unroll
    for (int m2 = 0; m2 < 64; m2++)
        z[m2] = W[(size_t)(64 * n1 + m2) * 4096 + col];

    // ---- in-place DIF DFT-64 (+i), radices [4,4,4] ----
    // stage 1: len=64, q=16; w1 = e^{2 pi i j/64} = expk[256 j]
    #pragma unroll
    for (int j = 0; j < 16; j++) {
        if (j == 0) { DIF4_NT(z[0], z[16], z[32], z[48]); }
        else {
            float2 e1 = expk[256 * j];
            DIF4(z[j], z[j + 16], z[j + 32], z[j + 48], e1.x, e1.y);
        }
    }
    // stage 2: len=16, q=4; w1 = e^{2 pi i j/16} = expk[1024 j]
    #pragma unroll
    for (int b = 0; b < 64; b += 16) {
        #pragma unroll
        for (int j = 0; j < 4; j++) {
            if (j == 0) { DIF4_NT(z[b], z[b + 4], z[b + 8], z[b + 12]); }
            else {
                float2 e1 = expk[1024 * j];
                DIF4(z[b + j], z[b + j + 4], z[b + j + 8], z[b + j + 12],
                     e1.x, e1.y);
            }
        }
    }
    // stage 3: len=4, twiddle-free
    #pragma unroll
    for (int b = 0; b < 64; b += 4) {
        DIF4_NT(z[b], z[b + 1], z[b + 2], z[b + 3]);
    }
    // position p holds ztrue[n1 + 32*n2], n2 = (p>>4) + (p&12) + ((p&3)<<4)

    // ---- fused Makhoul de-interleave along M + lane-contiguous stores ----
    // q < 1024:  Y[4q] = Re, Y[4q+2] = Im
    // q >= 1024: pp = 2047-q: Y[4pp+1] = Im, Y[4pp+3] = Re
    #pragma unroll
    for (int p = 0; p < 64; p++) {
        int n2 = (p >> 4) + (p & 12) + ((p & 3) << 4);
        int q  = n1 + 32 * n2;
        if (n2 < 32) {
            Y[(size_t)(4 * q + 0) * 4096 + col] = z[p].x;
            Y[(size_t)(4 * q + 2) * 4096 + col] = z[p].y;
        } else {
            int pp = 2047 - q;
            Y[(size_t)(4 * pp + 1) * 4096 + col] = z[p].y;
            Y[(size_t)(4 * pp + 3) * 4096 + col] = z[p].x;
        }
    }
}

// ---------------------------------------------------------------------------
// Fallback transpose (verified) — used only if ws is too small.
// ---------------------------------------------------------------------------
__global__ __launch_bounds__(256)
void transpose_inplace(float* d, int n)
{
    __shared__ float ta[64][65];
    __shared__ float tb[64][65];
    int ti = blockIdx.x, tj = blockIdx.y, b = blockIdx.z;
    if (tj < ti) return;
    float* base = d + (size_t)b * n * n;
    const int t  = threadIdx.x;
    const int c4 = t & 15;
    const int r0 = t >> 4;
    size_t offA = (size_t)(ti * 64) * n + tj * 64;
    size_t offB = (size_t)(tj * 64) * n + ti * 64;

    #pragma unroll
    for (int q = 0; q < 4; q++) {
        int r = r0 + 16 * q;
        float4 va = ((const float4*)(base + offA + (size_t)r * n))[c4];
        ta[r][4 * c4 + 0] = va.x; ta[r][4 * c4 + 1] = va.y;
        ta[r][4 * c4 + 2] = va.z; ta[r][4 * c4 + 3] = va.w;
    }
    if (ti != tj) {
        #pragma unroll
        for (int q = 0; q < 4; q++) {
            int r = r0 + 16 * q;
            float4 vb = ((const float4*)(base + offB + (size_t)r * n))[c4];
            tb[r][4 * c4 + 0] = vb.x; tb[r][4 * c4 + 1] = vb.y;
            tb[r][4 * c4 + 2] = vb.z; tb[r][4 * c4 + 3] = vb.w;
        }
    }
    __syncthreads();

    if (ti != tj) {
        #pragma unroll
        for (int q = 0; q < 4; q++) {
            int r = r0 + 16 * q;
            float4 o;
            o.x = tb[4 * c4 + 0][r]; o.y = tb[4 * c4 + 1][r];
            o.z = tb[4 * c4 + 2][r]; o.w = tb[4 * c4 + 3][r];
            ((float4*)(base + offA + (size_t)r * n))[c4] = o;
            float4 pp;
            pp.x = ta[4 * c4 + 0][r]; pp.y = ta[4 * c4 + 1][r];
            pp.z = ta[4 * c4 + 2][r]; pp.w = ta[4 * c4 + 3][r];
            ((float4*)(base + offB + (size_t)r * n))[c4] = pp;
        }
    } else {
        #pragma unroll
        for (int q = 0; q < 4; q++) {
            int r = r0 + 16 * q;
            float4 pp;
            pp.x = ta[4 * c4 + 0][r]; pp.y = ta[4 * c4 + 1][r];
            pp.z = ta[4 * c4 + 2][r]; pp.w = ta[4 * c4 + 3][r];
            ((float4*)(base + offA + (size_t)r * n))[c4] = pp;
        }
    }
}

extern "C" void kernel_launch(void* const* d_in, const int* in_sizes, int n_in,
                              void* d_out, int out_size, void* d_ws, size_t ws_size,
                              hipStream_t stream)
{
    const float*  x     = (const float*)d_in[0];
    const float2* expkM = (const float2*)d_in[1];   // (4096, 2) fp32
    const float2* expkN = (const float2*)d_in[2];   // (4096, 2) fp32
    float* out = (float*)d_out;

    const int B = in_sizes[0] / (4096 * 4096);      // = 2
    const int rows = B * 4096;

    // IDXST along N (contiguous rows of x) -> out.
    row_fft_kernel<true><<<rows, 512, 0, stream>>>(x, out, expkN);

    const size_t need = (size_t)B * 2048 * 4096 * sizeof(float2);  // 134 MB
    if (d_ws && ws_size >= need) {
        // Four-step IDCT along M, transpose-free.
        float2* W = (float2*)d_ws;
        col_pass1<<<dim3(64, 16, B), dim3(64, 4), 0, stream>>>(out, W, expkM);
        col_pass2<<<dim3(64,  8, B), dim3(64, 4), 0, stream>>>(W, out, expkM);
    } else {
        // Fallback: verified transpose + row IDCT + transpose.
        transpose_inplace<<<dim3(64, 64, B), dim3(256), 0, stream>>>(out, 4096);
        row_fft_kernel<false><<<rows, 512, 0, stream>>>(out, out, expkM);
        transpose_inplace<<<dim3(64, 64, B), dim3(256), 0, stream>>>(out, 4096);
    }
}

// Round 5
// 338.805 us; speedup vs baseline: 1.8700x; 1.8700x over previous
//
#include <hip/hip_runtime.h>

#define PI_F 3.14159265358979323846f
#define RSQ2 0.70710678118654752f

__device__ __forceinline__ float2 cmulf(float2 a, float c, float s) {
    return make_float2(a.x * c - a.y * s, a.x * s + a.y * c);
}

// ---- dual-complex (2 columns packed in float4: r0,i0,r1,i1) helpers ----
__device__ __forceinline__ float4 dadd(float4 a, float4 b) {
    return make_float4(a.x + b.x, a.y + b.y, a.z + b.z, a.w + b.w);
}
__device__ __forceinline__ float4 dsub(float4 a, float4 b) {
    return make_float4(a.x - b.x, a.y - b.y, a.z - b.z, a.w - b.w);
}
__device__ __forceinline__ float4 dmuli(float4 a) {         // * i
    return make_float4(-a.y, a.x, -a.w, a.z);
}
__device__ __forceinline__ float4 dmul(float4 a, float c, float s) {
    return make_float4(a.x * c - a.y * s, a.x * s + a.y * c,
                       a.z * c - a.w * s, a.z * s + a.w * c);
}
// In-place DIF radix-4 (+i convention), post-twiddles w,w^2,w^3. Matches the
// harness-verified scalar DIF4 of round 4.
__device__ __forceinline__ void dif4(float4& z0, float4& z1, float4& z2,
                                     float4& z3, float c1, float s1) {
    float4 t0 = dadd(z0, z2), t1 = dsub(z0, z2);
    float4 t2 = dadd(z1, z3), t3 = dsub(z1, z3);
    float c2 = c1 * c1 - s1 * s1, s2 = 2.0f * c1 * s1;
    float c3 = c1 * c2 - s1 * s2, s3 = c1 * s2 + s1 * c2;
    z0 = dadd(t0, t2);
    z1 = dmul(dadd(t1, dmuli(t3)), c1, s1);
    z2 = dmul(dsub(t0, t2), c2, s2);
    z3 = dmul(dsub(t1, dmuli(t3)), c3, s3);
}
__device__ __forceinline__ void dif4nt(float4& z0, float4& z1, float4& z2,
                                       float4& z3) {
    float4 t0 = dadd(z0, z2), t1 = dsub(z0, z2);
    float4 t2 = dadd(z1, z3), t3 = dsub(z1, z3);
    z0 = dadd(t0, t2);
    z1 = dadd(t1, dmuli(t3));
    z2 = dsub(t0, t2);
    z3 = dsub(t1, dmuli(t3));
}
// i^qd * e  (qd wave-uniform)
__device__ __forceinline__ float2 quadrot(float2 e, int qd) {
    switch (qd & 3) {
        case 0:  return make_float2( e.x,  e.y);
        case 1:  return make_float2(-e.y,  e.x);
        case 2:  return make_float2(-e.x, -e.y);
        default: return make_float2( e.y, -e.x);
    }
}

// LDS float2-index swizzle for K1 (verified round 2).
#define SW(e) ((e) ^ ((((e) >> 4) & 3) * 5))

// Radix-4 Stockham butterfly for K1 (verified).
#define BFLY4(v0, v1, v2, v3, o0, o1, o2, o3)                                  \
    {                                                                          \
        float a0r = v0.x + v2.x, a0i = v0.y + v2.y;                            \
        float a1r = v0.x - v2.x, a1i = v0.y - v2.y;                            \
        float a2r = v1.x + v3.x, a2i = v1.y + v3.y;                            \
        float a3r = v1.x - v3.x, a3i = v1.y - v3.y;                            \
        o0 = make_float2(a0r + a2r, a0i + a2i);                                \
        o1 = make_float2(a1r - a3i, a1i + a3r);                                \
        o2 = make_float2(a0r - a2r, a0i - a2i);                                \
        o3 = make_float2(a1r + a3i, a1i - a3r);                                \
    }

// ---------------------------------------------------------------------------
// K1: one workgroup (512 threads) = one row of length 4096.  (VERIFIED)
// ---------------------------------------------------------------------------
template<bool IDXST>
__global__ __launch_bounds__(512, 8)
void row_fft_kernel(const float* __restrict__ in, float* __restrict__ out,
                    const float2* __restrict__ expk)
{
    __shared__ float smem[8192];
    float*  xs   = smem;
    float2* bufB = (float2*)smem;
    float2* bufA = (float2*)(smem + 4096);

    const int t = threadIdx.x;
    const size_t row = blockIdx.x;
    const float* src = in  + row * 4096;
    float*       dst = out + row * 4096;

    {
        const float4* s4 = (const float4*)src;
        float4* x4 = (float4*)xs;
        x4[t]       = s4[t];
        x4[t + 512] = s4[t + 512];
    }
    __syncthreads();

    float2 z[4];
    #pragma unroll
    for (int i = 0; i < 4; i++) {
        int k = t + 512 * i;
        float Xa, Xra, Xb, Xrb;
        if (IDXST) {
            Xa  = xs[(4096 - k) & 4095];
            Xra = xs[k];
            Xb  = xs[2048 - k];
            Xrb = xs[2048 + k];
            if (k == 0) { Xa = 0.0f; Xra = 0.0f; }
        } else {
            Xa  = xs[k];
            Xra = xs[(4096 - k) & 4095];
            Xb  = xs[2048 + k];
            Xrb = xs[2048 - k];
            if (k == 0) Xra = 0.0f;
        }
        float2 ea = expk[k];
        float2 eb = expk[k + 2048];
        float Var = 0.5f * (Xa * ea.x + Xra * ea.y);
        float Vai = 0.5f * (Xa * ea.y - Xra * ea.x);
        float Vbr = 0.5f * (Xb * eb.x + Xrb * eb.y);
        float Vbi = 0.5f * (Xb * eb.y - Xrb * eb.x);
        float Ar = Var + Vbr, Ai = Vai + Vbi;
        float Dr = Var - Vbr, Di = Vai - Vbi;
        float cw, sw;
        __sincosf(PI_F * (float)k * (1.0f / 2048.0f), &sw, &cw);
        float Br = Dr * cw - Di * sw;
        float Bi = Dr * sw + Di * cw;
        z[i] = make_float2(Ar - Bi, Ai + Br);
    }

    {
        float2 v0 = z[0], v1 = z[1], v2 = z[2], v3 = z[3];
        int e = t << 2;
        BFLY4(v0, v1, v2, v3,
              bufA[SW(e)], bufA[SW(e + 1)], bufA[SW(e + 2)], bufA[SW(e + 3)]);
    }
    __syncthreads();

    float2* sb = bufA;
    float2* db = bufB;
    int Ns = 4;
    #pragma unroll
    for (int s = 1; s < 5; s++) {
        const int ls = 2 * s;
        const int j = t;
        float2 v0 = sb[SW(j)];
        float2 v1 = sb[SW(j + 512)];
        float2 v2 = sb[SW(j + 1024)];
        float2 v3 = sb[SW(j + 1536)];
        int jm = j & (Ns - 1);
        float c1, s1;
        if (s <= 2) {
            float2 e1 = expk[jm << (12 - 2 * s)];
            c1 = e1.x; s1 = e1.y;
        } else {
            __sincosf((0.5f * PI_F) * (float)jm / (float)Ns, &s1, &c1);
        }
        float c2 = c1 * c1 - s1 * s1, s2 = 2.0f * c1 * s1;
        float c3 = c1 * c2 - s1 * s2, s3 = c1 * s2 + s1 * c2;
        v1 = cmulf(v1, c1, s1);
        v2 = cmulf(v2, c2, s2);
        v3 = cmulf(v3, c3, s3);
        int idxD = ((j >> ls) << (ls + 2)) | jm;
        BFLY4(v0, v1, v2, v3,
              db[SW(idxD)], db[SW(idxD + Ns)],
              db[SW(idxD + 2 * Ns)], db[SW(idxD + 3 * Ns)]);
        __syncthreads();
        float2* tmp = sb; sb = db; db = tmp;
        Ns <<= 2;
    }

    {
        int j  = t;
        int jB = 1023 - t;
        float2 a0 = sb[SW(j)];
        float2 a1 = sb[SW(j + 1024)];
        float2 b0 = sb[SW(jB)];
        float2 b1 = sb[SW(jB + 1024)];
        float sA, cA, sB, cB;
        __sincosf(PI_F * (float)j  * (1.0f / 1024.0f), &sA, &cA);
        __sincosf(PI_F * (float)jB * (1.0f / 1024.0f), &sB, &cB);
        float2 wa1 = cmulf(a1, cA, sA);
        float2 wb1 = cmulf(b1, cB, sB);
        float2 zA0 = make_float2(a0.x + wa1.x, a0.y + wa1.y);
        float2 zA1 = make_float2(a0.x - wa1.x, a0.y - wa1.y);
        float2 zB0 = make_float2(b0.x + wb1.x, b0.y + wb1.y);
        float2 zB1 = make_float2(b0.x - wb1.x, b0.y - wb1.y);
        float4 oA, oB;
        if (IDXST) {
            oA = make_float4(zA0.x, -zB1.y, zA0.y, -zB1.x);
            oB = make_float4(zB0.x, -zA1.y, zB0.y, -zA1.x);
        } else {
            oA = make_float4(zA0.x,  zB1.y, zA0.y,  zB1.x);
            oB = make_float4(zB0.x,  zA1.y, zB0.y,  zA1.x);
        }
        float4* d4 = (float4*)dst;
        d4[j]  = oA;
        d4[jB] = oB;
    }
}

// ---------------------------------------------------------------------------
// Four-step column IDCT along M, transpose-free.  k = 64*m1 + m2, n = n1+32*n2.
// P1: DFT-32 over m1 split across 8 threads x 4 points, LDS exchange between
//     stages; Makhoul Z-build fused; four-step twiddle at store.
// P2: DFT-64 over m2 split across 8 threads x 8 points; fused de-interleave.
// Each lane handles 2 columns (float4 dual-complex). NO per-thread arrays.
// ---------------------------------------------------------------------------

// one-column Makhoul V/A/B combine (verified math)
__device__ __forceinline__ float2 zb1(float Xa, float Xra, float Xb, float Xrb,
                                      float2 ea, float2 eb, float cw, float sw) {
    float Var = 0.5f * (Xa * ea.x + Xra * ea.y);
    float Vai = 0.5f * (Xa * ea.y - Xra * ea.x);
    float Vbr = 0.5f * (Xb * eb.x + Xrb * eb.y);
    float Vbi = 0.5f * (Xb * eb.y - Xrb * eb.x);
    float Ar = Var + Vbr, Ai = Vai + Vbi;
    float Dr = Var - Vbr, Di = Vai - Vbi;
    float Br = Dr * cw - Di * sw;
    float Bi = Dr * sw + Di * cw;
    return make_float2(Ar - Bi, Ai + Br);
}

__device__ __forceinline__ float4 zbuild(const float* __restrict__ G,
                                         const float2* __restrict__ expk,
                                         int m1, int m2, int colf, float2 u) {
    int k = 64 * m1 + m2;
    float2 Xa  = *(const float2*)&G[(size_t)k * 4096 + colf];
    float2 Xra = make_float2(0.0f, 0.0f);
    if (k != 0) Xra = *(const float2*)&G[(size_t)(4096 - k) * 4096 + colf];
    float2 Xb  = *(const float2*)&G[(size_t)(2048 + k) * 4096 + colf];
    float2 Xrb = *(const float2*)&G[(size_t)(2048 - k) * 4096 + colf];
    float2 ea = expk[k];
    float2 eb = expk[k + 2048];
    // e^{i pi k/2048} = u * e^{i pi m1/32}
    float2 ev = expk[256 * (m1 & 15)];
    float vc = (m1 < 16) ? ev.x : -ev.y;
    float vs = (m1 < 16) ? ev.y :  ev.x;
    float cw = u.x * vc - u.y * vs;
    float sw = u.x * vs + u.y * vc;
    float2 lo = zb1(Xa.x, Xra.x, Xb.x, Xrb.x, ea, eb, cw, sw);
    float2 hi = zb1(Xa.y, Xra.y, Xb.y, Xrb.y, ea, eb, cw, sw);
    return make_float4(lo.x, lo.y, hi.x, hi.y);
}

__global__ __launch_bounds__(512, 4)
void col_pass1(const float* __restrict__ g, float2* __restrict__ wbuf,
               const float2* __restrict__ expk)
{
    __shared__ float4 zs[32 * 64];                        // 32 KB
    const int c    = threadIdx.x;                         // lane = col-pair
    const int gq   = threadIdx.y;                         // 0..7
    const int colf = 2 * (blockIdx.x * 64 + c);           // float col
    const int m2   = blockIdx.y;                          // 0..63
    const float* G = g    + (size_t)blockIdx.z * 4096 * 4096;
    float2*      W = wbuf + (size_t)blockIdx.z * 2048 * 4096;

    const float2 u = expk[4 * m2];                        // e^{i pi m2/2048}

    // ---- Z-build: points m1 = gq, gq+8, gq+16, gq+24 ----
    float4 z0 = zbuild(G, expk, gq,      m2, colf, u);
    float4 z1 = zbuild(G, expk, gq + 8,  m2, colf, u);
    float4 z2 = zbuild(G, expk, gq + 16, m2, colf, u);
    float4 z3 = zbuild(G, expk, gq + 24, m2, colf, u);

    // ---- stage 1 (len=32): butterfly j=gq, w1 = e^{2 pi i gq/32} ----
    if (gq == 0) { dif4nt(z0, z1, z2, z3); }
    else { float2 e1 = expk[512 * gq]; dif4(z0, z1, z2, z3, e1.x, e1.y); }
    zs[(gq     ) * 64 + c] = z0;
    zs[(gq +  8) * 64 + c] = z1;
    zs[(gq + 16) * 64 + c] = z2;
    zs[(gq + 24) * 64 + c] = z3;
    __syncthreads();

    // ---- stage 2 (len=8): butterfly (b+j, +2, +4, +6), b=8*(gq>>1), j=gq&1
    {
        int b = 8 * (gq >> 1), j = gq & 1;
        float4 y0 = zs[(b + j    ) * 64 + c];
        float4 y1 = zs[(b + j + 2) * 64 + c];
        float4 y2 = zs[(b + j + 4) * 64 + c];
        float4 y3 = zs[(b + j + 6) * 64 + c];
        if (j == 0) { dif4nt(y0, y1, y2, y3); }
        else        { dif4(y0, y1, y2, y3, RSQ2, RSQ2); }
        zs[(b + j    ) * 64 + c] = y0;
        zs[(b + j + 2) * 64 + c] = y1;
        zs[(b + j + 4) * 64 + c] = y2;
        zs[(b + j + 6) * 64 + c] = y3;
    }
    __syncthreads();

    // ---- stage 3 (radix-2 adjacent) on positions 4gq..4gq+3, then store ----
    {
        float4 w0 = zs[(4 * gq    ) * 64 + c];
        float4 w1 = zs[(4 * gq + 1) * 64 + c];
        float4 w2 = zs[(4 * gq + 2) * 64 + c];
        float4 w3 = zs[(4 * gq + 3) * 64 + c];
        float4 s0 = dadd(w0, w1), s1 = dsub(w0, w1);
        float4 s2 = dadd(w2, w3), s3 = dsub(w2, w3);

        // position p holds Zhat[n1], n1 = (p>>3)+4*((p>>1)&3)+16*(p&1)
        // four-step twiddle e^{2 pi i n1 m2/2048} = i^(a>>9) * expk[8*(a&511)]
#define P1_STORE(v, p) {                                                       \
        int n1_ = ((p) >> 3) + 4 * (((p) >> 1) & 3) + 16 * ((p) & 1);          \
        int a_  = n1_ * m2;                                                    \
        float2 tw = quadrot(expk[8 * (a_ & 511)], a_ >> 9);                    \
        *(float4*)&W[(size_t)(64 * n1_ + m2) * 4096 + colf] =                  \
            dmul(v, tw.x, tw.y); }
        P1_STORE(s0, 4 * gq + 0);
        P1_STORE(s1, 4 * gq + 1);
        P1_STORE(s2, 4 * gq + 2);
        P1_STORE(s3, 4 * gq + 3);
#undef P1_STORE
    }
}

__global__ __launch_bounds__(512, 4)
void col_pass2(const float2* __restrict__ wbuf, float* __restrict__ y,
               const float2* __restrict__ expk)
{
    __shared__ float4 zs[64 * 64];                        // 64 KB
    const int c    = threadIdx.x;
    const int gq   = threadIdx.y;                         // 0..7
    const int colf = 2 * (blockIdx.x * 64 + c);
    const int n1   = blockIdx.y;                          // 0..31
    const float2* W = wbuf + (size_t)blockIdx.z * 2048 * 4096;
    float*        Y = y    + (size_t)blockIdx.z * 4096 * 4096;

    const int j0 = 2 * gq, j1 = 2 * gq + 1;

    // ---- load m2 = {j, j+16, j+32, j+48} for j = j0, j1 ----
    float4 a0 = *(const float4*)&W[(size_t)(64 * n1 + j0     ) * 4096 + colf];
    float4 a1 = *(const float4*)&W[(size_t)(64 * n1 + j0 + 16) * 4096 + colf];
    float4 a2 = *(const float4*)&W[(size_t)(64 * n1 + j0 + 32) * 4096 + colf];
    float4 a3 = *(const float4*)&W[(size_t)(64 * n1 + j0 + 48) * 4096 + colf];
    float4 b0 = *(const float4*)&W[(size_t)(64 * n1 + j1     ) * 4096 + colf];
    float4 b1 = *(const float4*)&W[(size_t)(64 * n1 + j1 + 16) * 4096 + colf];
    float4 b2 = *(const float4*)&W[(size_t)(64 * n1 + j1 + 32) * 4096 + colf];
    float4 b3 = *(const float4*)&W[(size_t)(64 * n1 + j1 + 48) * 4096 + colf];

    // ---- stage 1 (len=64): w1 = e^{2 pi i j/64} = expk[256 j] ----
    if (gq == 0) { dif4nt(a0, a1, a2, a3); }
    else { float2 e1 = expk[256 * j0]; dif4(a0, a1, a2, a3, e1.x, e1.y); }
    { float2 e1 = expk[256 * j1]; dif4(b0, b1, b2, b3, e1.x, e1.y); }
    zs[(j0     ) * 64 + c] = a0;
    zs[(j0 + 16) * 64 + c] = a1;
    zs[(j0 + 32) * 64 + c] = a2;
    zs[(j0 + 48) * 64 + c] = a3;
    zs[(j1     ) * 64 + c] = b0;
    zs[(j1 + 16) * 64 + c] = b1;
    zs[(j1 + 32) * 64 + c] = b2;
    zs[(j1 + 48) * 64 + c] = b3;
    __syncthreads();

    // ---- stage 2 (len=16): butterflies t = j0, j1; b2=16*(t>>2), j=t&3 ----
    {
        int bb = 16 * (j0 >> 2), jj = j0 & 3;
        float4 y0 = zs[(bb + jj     ) * 64 + c];
        float4 y1 = zs[(bb + jj +  4) * 64 + c];
        float4 y2 = zs[(bb + jj +  8) * 64 + c];
        float4 y3 = zs[(bb + jj + 12) * 64 + c];
        if (jj == 0) { dif4nt(y0, y1, y2, y3); }
        else { float2 e1 = expk[1024 * jj]; dif4(y0, y1, y2, y3, e1.x, e1.y); }
        zs[(bb + jj     ) * 64 + c] = y0;
        zs[(bb + jj +  4) * 64 + c] = y1;
        zs[(bb + jj +  8) * 64 + c] = y2;
        zs[(bb + jj + 12) * 64 + c] = y3;
    }
    {
        int bb = 16 * (j1 >> 2), jj = j1 & 3;
        float4 y0 = zs[(bb + jj     ) * 64 + c];
        float4 y1 = zs[(bb + jj +  4) * 64 + c];
        float4 y2 = zs[(bb + jj +  8) * 64 + c];
        float4 y3 = zs[(bb + jj + 12) * 64 + c];
        if (jj == 0) { dif4nt(y0, y1, y2, y3); }
        else { float2 e1 = expk[1024 * jj]; dif4(y0, y1, y2, y3, e1.x, e1.y); }
        zs[(bb + jj     ) * 64 + c] = y0;
        zs[(bb + jj +  4) * 64 + c] = y1;
        zs[(bb + jj +  8) * 64 + c] = y2;
        zs[(bb + jj + 12) * 64 + c] = y3;
    }
    __syncthreads();

    // ---- stage 3 (len=4, NT) on positions 8gq..8gq+7, then store ----
    float4 w0 = zs[(8 * gq + 0) * 64 + c];
    float4 w1 = zs[(8 * gq + 1) * 64 + c];
    float4 w2 = zs[(8 * gq + 2) * 64 + c];
    float4 w3 = zs[(8 * gq + 3) * 64 + c];
    float4 w4 = zs[(8 * gq + 4) * 64 + c];
    float4 w5 = zs[(8 * gq + 5) * 64 + c];
    float4 w6 = zs[(8 * gq + 6) * 64 + c];
    float4 w7 = zs[(8 * gq + 7) * 64 + c];
    dif4nt(w0, w1, w2, w3);
    dif4nt(w4, w5, w6, w7);

    // position p holds z[n1+32*n2], n2 = (p>>4)+(p&12)+((p&3)<<4)
    // de-interleave: q<1024: Y[4q]=Re, Y[4q+2]=Im; else pp=2047-q:
    // Y[4pp+1]=Im, Y[4pp+3]=Re.   (p&3)<2 <=> n2<32.
#define P2_STORE(v, p) {                                                       \
    int n2_ = ((p) >> 4) + ((p) & 12) + (((p) & 3) << 4);                      \
    int q_  = n1 + 32 * n2_;                                                   \
    if (((p) & 3) < 2) {                                                       \
        *(float2*)&Y[(size_t)(4 * q_ + 0) * 4096 + colf] =                     \
            make_float2(v.x, v.z);                                             \
        *(float2*)&Y[(size_t)(4 * q_ + 2) * 4096 + colf] =                     \
            make_float2(v.y, v.w);                                             \
    } else {                                                                   \
        int pp_ = 2047 - q_;                                                   \
        *(float2*)&Y[(size_t)(4 * pp_ + 1) * 4096 + colf] =                    \
            make_float2(v.y, v.w);                                             \
        *(float2*)&Y[(size_t)(4 * pp_ + 3) * 4096 + colf] =                    \
            make_float2(v.x, v.z);                                             \
    } }
    P2_STORE(w0, 8 * gq + 0);
    P2_STORE(w1, 8 * gq + 1);
    P2_STORE(w2, 8 * gq + 2);
    P2_STORE(w3, 8 * gq + 3);
    P2_STORE(w4, 8 * gq + 4);
    P2_STORE(w5, 8 * gq + 5);
    P2_STORE(w6, 8 * gq + 6);
    P2_STORE(w7, 8 * gq + 7);
#undef P2_STORE
}

// ---------------------------------------------------------------------------
// Fallback transpose (verified) — used only if ws is too small.
// ---------------------------------------------------------------------------
__global__ __launch_bounds__(256)
void transpose_inplace(float* d, int n)
{
    __shared__ float ta[64][65];
    __shared__ float tb[64][65];
    int ti = blockIdx.x, tj = blockIdx.y, b = blockIdx.z;
    if (tj < ti) return;
    float* base = d + (size_t)b * n * n;
    const int t  = threadIdx.x;
    const int c4 = t & 15;
    const int r0 = t >> 4;
    size_t offA = (size_t)(ti * 64) * n + tj * 64;
    size_t offB = (size_t)(tj * 64) * n + ti * 64;

    #pragma unroll
    for (int q = 0; q < 4; q++) {
        int r = r0 + 16 * q;
        float4 va = ((const float4*)(base + offA + (size_t)r * n))[c4];
        ta[r][4 * c4 + 0] = va.x; ta[r][4 * c4 + 1] = va.y;
        ta[r][4 * c4 + 2] = va.z; ta[r][4 * c4 + 3] = va.w;
    }
    if (ti != tj) {
        #pragma unroll
        for (int q = 0; q < 4; q++) {
            int r = r0 + 16 * q;
            float4 vb = ((const float4*)(base + offB + (size_t)r * n))[c4];
            tb[r][4 * c4 + 0] = vb.x; tb[r][4 * c4 + 1] = vb.y;
            tb[r][4 * c4 + 2] = vb.z; tb[r][4 * c4 + 3] = vb.w;
        }
    }
    __syncthreads();

    if (ti != tj) {
        #pragma unroll
        for (int q = 0; q < 4; q++) {
            int r = r0 + 16 * q;
            float4 o;
            o.x = tb[4 * c4 + 0][r]; o.y = tb[4 * c4 + 1][r];
            o.z = tb[4 * c4 + 2][r]; o.w = tb[4 * c4 + 3][r];
            ((float4*)(base + offA + (size_t)r * n))[c4] = o;
            float4 pp;
            pp.x = ta[4 * c4 + 0][r]; pp.y = ta[4 * c4 + 1][r];
            pp.z = ta[4 * c4 + 2][r]; pp.w = ta[4 * c4 + 3][r];
            ((float4*)(base + offB + (size_t)r * n))[c4] = pp;
        }
    } else {
        #pragma unroll
        for (int q = 0; q < 4; q++) {
            int r = r0 + 16 * q;
            float4 pp;
            pp.x = ta[4 * c4 + 0][r]; pp.y = ta[4 * c4 + 1][r];
            pp.z = ta[4 * c4 + 2][r]; pp.w = ta[4 * c4 + 3][r];
            ((float4*)(base + offA + (size_t)r * n))[c4] = pp;
        }
    }
}

extern "C" void kernel_launch(void* const* d_in, const int* in_sizes, int n_in,
                              void* d_out, int out_size, void* d_ws, size_t ws_size,
                              hipStream_t stream)
{
    const float*  x     = (const float*)d_in[0];
    const float2* expkM = (const float2*)d_in[1];   // (4096, 2) fp32
    const float2* expkN = (const float2*)d_in[2];   // (4096, 2) fp32
    float* out = (float*)d_out;

    const int B = in_sizes[0] / (4096 * 4096);      // = 2
    const int rows = B * 4096;

    // IDXST along N (contiguous rows of x) -> out.
    row_fft_kernel<true><<<rows, 512, 0, stream>>>(x, out, expkN);

    const size_t need = (size_t)B * 2048 * 4096 * sizeof(float2);  // 134 MB
    if (d_ws && ws_size >= need) {
        float2* W = (float2*)d_ws;
        col_pass1<<<dim3(32, 64, B), dim3(64, 8), 0, stream>>>(out, W, expkM);
        col_pass2<<<dim3(32, 32, B), dim3(64, 8), 0, stream>>>(W, out, expkM);
    } else {
        transpose_inplace<<<dim3(64, 64, B), dim3(256), 0, stream>>>(out, 4096);
        row_fft_kernel<false><<<rows, 512, 0, stream>>>(out, out, expkM);
        transpose_inplace<<<dim3(64, 64, B), dim3(256), 0, stream>>>(out, 4096);
    }
}